// Round 3
// baseline (139.099 us; speedup 1.0000x reference)
//
#include <hip/hip_runtime.h>
#include <stdint.h>

#define MM 8
#define KK 8192
#define NN 8192
#define KC 128            // k-chunk per gemm block
#define FP8MAXV 448.0f

typedef float f32x4 __attribute__((ext_vector_type(4)));

// ---------------------------------------------------------------------------
// Bit-exact round-to-nearest-even f32 -> fp8 e4m3fn -> f32 (|v| <= ~448).
// Normal range (|v| >= 2^-6): keep 1+3 mantissa bits via add-half-and-truncate.
// Subnormal range (|v| < 2^-6): quantum is 2^-9; rintf is RNE (v_rndne).
// ---------------------------------------------------------------------------
__device__ __forceinline__ float fp8_e4m3_round(float v) {
    uint32_t u = __float_as_uint(v);
    uint32_t mag = u & 0x7fffffffu;
    if (mag >= 0x3C800000u) {            // |v| >= 2^-6 : normal e4m3
        uint32_t lsb = (u >> 20) & 1u;   // RNE: add (half - 1) + lsb
        uint32_t r = u + 0x0007FFFFu + lsb;
        r &= 0xFFF00000u;                // keep sign + exp + 3 mantissa bits
        return __uint_as_float(r);
    }
    return rintf(v * 512.0f) * (1.0f / 512.0f);
}

// ---------------------------------------------------------------------------
// Kernel 1 (fused): blocks 0..MM-1: per-row amax -> scale, quantize x,
// store transposed xqT[k][m] into ws. blocks MM..MM+255: out = bias.
// ws layout (floats): [0..7] = x_scale_inv per row; [64 ..] = xqT (KK*MM)
// ---------------------------------------------------------------------------
__global__ __launch_bounds__(256) void prep_init_kernel(const float* __restrict__ x,
                                                        const float* __restrict__ bias,
                                                        float* __restrict__ ws,
                                                        float* __restrict__ out) {
    if (blockIdx.x >= MM) {
        int idx = (blockIdx.x - MM) * 256 + threadIdx.x;  // covers MM*NN
        out[idx] = bias[idx & (NN - 1)];
        return;
    }
    const int m = blockIdx.x;
    const int tid = threadIdx.x;
    const float* row = x + (size_t)m * KK;

    float amax = 0.0f;
    for (int k = tid * 4; k < KK; k += 256 * 4) {
        f32x4 v = *(const f32x4*)(row + k);
        amax = fmaxf(amax, fmaxf(fmaxf(fabsf(v.x), fabsf(v.y)),
                                 fmaxf(fabsf(v.z), fabsf(v.w))));
    }
#pragma unroll
    for (int off = 32; off >= 1; off >>= 1)
        amax = fmaxf(amax, __shfl_xor(amax, off, 64));

    __shared__ float sred[4];
    __shared__ float sscale;
    if ((tid & 63) == 0) sred[tid >> 6] = amax;
    __syncthreads();
    if (tid == 0) {
        float a = fmaxf(fmaxf(sred[0], sred[1]), fmaxf(sred[2], sred[3]));
        float scale = (a > 0.0f) ? (FP8MAXV / a) : 1.0f;
        sscale = scale;
        ws[m] = 1.0f / scale;            // matches reference's 1.0/x_scale
    }
    __syncthreads();
    const float scale = sscale;

    float* xqT = ws + 64;
    for (int k = tid; k < KK; k += 256)
        xqT[(size_t)k * MM + m] = fp8_e4m3_round(row[k] * scale);
}

// ---------------------------------------------------------------------------
// Kernel 2: split-K GEMV. 256 threads/block, each thread owns 4 consecutive
// output columns (dwordx4 W loads -> 1 KiB/wave/instr). grid.x = NN/1024
// column tiles, grid.y = KK/KC k-chunks. Activation chunk broadcast from LDS.
// Partials atomically accumulated onto bias-preinitialized out.
// R2: plain (cached) loads — R1's nontemporal flag is the suspected 2x regression.
// ---------------------------------------------------------------------------
__global__ __launch_bounds__(256) void gemm_kernel(const float* __restrict__ W,
                                                   const float* __restrict__ wsinv,
                                                   const float* __restrict__ ws,
                                                   float* __restrict__ out) {
    const int n4 = (blockIdx.x * 256 + threadIdx.x) * 4;
    const int k0 = blockIdx.y * KC;

    __shared__ float sxq[KC * MM];                 // 4 KB
    ((f32x4*)sxq)[threadIdx.x] =
        ((const f32x4*)(ws + 64 + (size_t)k0 * MM))[threadIdx.x];
    __syncthreads();

    f32x4 acc[MM];
#pragma unroll
    for (int m = 0; m < MM; ++m) acc[m] = (f32x4)0.0f;

    const float* Wp = W + (size_t)k0 * NN + n4;
#pragma unroll 8
    for (int k = 0; k < KC; ++k) {
        f32x4 w = *(const f32x4*)(Wp + (size_t)k * NN);
        const f32x4* a4 = (const f32x4*)(sxq + k * MM);
        f32x4 a0 = a4[0];
        f32x4 a1 = a4[1];
        acc[0] += w * a0.x;
        acc[1] += w * a0.y;
        acc[2] += w * a0.z;
        acc[3] += w * a0.w;
        acc[4] += w * a1.x;
        acc[5] += w * a1.y;
        acc[6] += w * a1.z;
        acc[7] += w * a1.w;
    }

    const f32x4 wsn = *(const f32x4*)(wsinv + n4);
#pragma unroll
    for (int m = 0; m < MM; ++m) {
        f32x4 r = acc[m] * (ws[m] * wsn);
        float* o = out + (size_t)m * NN + n4;
        unsafeAtomicAdd(o + 0, r.x);
        unsafeAtomicAdd(o + 1, r.y);
        unsafeAtomicAdd(o + 2, r.z);
        unsafeAtomicAdd(o + 3, r.w);
    }
}

extern "C" void kernel_launch(void* const* d_in, const int* in_sizes, int n_in,
                              void* d_out, int out_size, void* d_ws, size_t ws_size,
                              hipStream_t stream) {
    const float* x     = (const float*)d_in[0];   // [M,K] f32
    const float* W     = (const float*)d_in[1];   // [K,N] f32 (fp8 values)
    const float* wsinv = (const float*)d_in[2];   // [N]   f32
    const float* bias  = (const float*)d_in[3];   // [N]   f32
    float* out = (float*)d_out;                   // [M,N] f32
    float* ws  = (float*)d_ws;                    // scales + xqT (~257 KB)

    prep_init_kernel<<<MM + (MM * NN) / 256, 256, 0, stream>>>(x, bias, ws, out);
    gemm_kernel<<<dim3(NN / 1024, KK / KC), 256, 0, stream>>>(W, wsinv, ws, out);
}

// Round 4
// 65.227 us; speedup vs baseline: 2.1325x; 2.1325x over previous
//
#include <hip/hip_runtime.h>
#include <stdint.h>

#define MM 8
#define KK 8192
#define NN 8192
#define KC 256                 // k-chunk per gemm block
#define KSPLIT (KK / KC)       // 32 partial slabs
#define FP8MAXV 448.0f

typedef float f32x4 __attribute__((ext_vector_type(4)));
typedef float f32x2 __attribute__((ext_vector_type(2)));

// ws layout (floats):
//   [0..7]                    x_scale_inv per row
//   [64 .. 64+KK*MM)          xqT transposed quantized activations [k][m]
//   [PART_OFF ..)             partials [KSPLIT][MM][NN]
#define XQT_OFF 64
#define PART_OFF (XQT_OFF + KK * MM)   // 65600, 16B-aligned

// ---------------------------------------------------------------------------
// Bit-exact RNE f32 -> fp8 e4m3fn -> f32 (|v| <= 448).
// ---------------------------------------------------------------------------
__device__ __forceinline__ float fp8_e4m3_round(float v) {
    uint32_t u = __float_as_uint(v);
    uint32_t mag = u & 0x7fffffffu;
    if (mag >= 0x3C800000u) {            // |v| >= 2^-6 : normal e4m3
        uint32_t lsb = (u >> 20) & 1u;
        uint32_t r = u + 0x0007FFFFu + lsb;
        r &= 0xFFF00000u;
        return __uint_as_float(r);
    }
    return rintf(v * 512.0f) * (1.0f / 512.0f);   // subnormal quantum 2^-9
}

// ---------------------------------------------------------------------------
// Kernel 1: per-row amax -> scale; quantize x; store xqT[k][m].
// ---------------------------------------------------------------------------
__global__ __launch_bounds__(256) void prep_kernel(const float* __restrict__ x,
                                                   float* __restrict__ ws) {
    const int m = blockIdx.x;
    const int tid = threadIdx.x;
    const float* row = x + (size_t)m * KK;

    float amax = 0.0f;
    for (int k = tid * 4; k < KK; k += 256 * 4) {
        f32x4 v = *(const f32x4*)(row + k);
        amax = fmaxf(amax, fmaxf(fmaxf(fabsf(v.x), fabsf(v.y)),
                                 fmaxf(fabsf(v.z), fabsf(v.w))));
    }
#pragma unroll
    for (int off = 32; off >= 1; off >>= 1)
        amax = fmaxf(amax, __shfl_xor(amax, off, 64));

    __shared__ float sred[4];
    __shared__ float sscale;
    if ((tid & 63) == 0) sred[tid >> 6] = amax;
    __syncthreads();
    if (tid == 0) {
        float a = fmaxf(fmaxf(sred[0], sred[1]), fmaxf(sred[2], sred[3]));
        float scale = (a > 0.0f) ? (FP8MAXV / a) : 1.0f;
        sscale = scale;
        ws[m] = 1.0f / scale;
    }
    __syncthreads();
    const float scale = sscale;

    float* xqT = ws + XQT_OFF;
    for (int k = tid; k < KK; k += 256)
        xqT[(size_t)k * MM + m] = fp8_e4m3_round(row[k] * scale);
}

// ---------------------------------------------------------------------------
// Kernel 2a: split-K GEMV partials, NO atomics. 1 column/thread, KC=256.
// grid (NN/256, KSPLIT) = 1024 blocks -> 16 waves/CU. Scaled partial rows
// stored coalesced to ws. Accumulators packed f32x2 -> v_pk_fma_f32.
// ---------------------------------------------------------------------------
__global__ __launch_bounds__(256, 4) void gemm_partial(const float* __restrict__ W,
                                                       const float* __restrict__ wsinv,
                                                       const float* __restrict__ ws,
                                                       float* __restrict__ part) {
    const int n  = blockIdx.x * 256 + threadIdx.x;
    const int c  = blockIdx.y;
    const int k0 = c * KC;

    __shared__ float sxq[KC * MM];                 // 8 KB
    {
        const f32x4* src = (const f32x4*)(ws + XQT_OFF + (size_t)k0 * MM);
        ((f32x4*)sxq)[threadIdx.x]       = src[threadIdx.x];
        ((f32x4*)sxq)[threadIdx.x + 256] = src[threadIdx.x + 256];
    }
    __syncthreads();

    f32x2 acc[4];
#pragma unroll
    for (int i = 0; i < 4; ++i) acc[i] = (f32x2)0.0f;

    const float* Wp = W + (size_t)k0 * NN + n;
#pragma unroll 8
    for (int k = 0; k < KC; ++k) {
        float w = Wp[(size_t)k * NN];
        const f32x2* a2 = (const f32x2*)(sxq + k * MM);   // broadcast reads
        acc[0] += a2[0] * w;
        acc[1] += a2[1] * w;
        acc[2] += a2[2] * w;
        acc[3] += a2[3] * w;
    }

    const float wsn = wsinv[n];
    float* p = part + ((size_t)c * MM) * NN + n;
#pragma unroll
    for (int i = 0; i < 4; ++i) {
        p[(size_t)(2 * i + 0) * NN] = acc[i].x * (ws[2 * i + 0] * wsn);
        p[(size_t)(2 * i + 1) * NN] = acc[i].y * (ws[2 * i + 1] * wsn);
    }
}

// ---------------------------------------------------------------------------
// Kernel 3a: reduce KSPLIT partials + bias -> out. One thread per output.
// ---------------------------------------------------------------------------
__global__ __launch_bounds__(256) void reduce_kernel(const float* __restrict__ part,
                                                     const float* __restrict__ bias,
                                                     float* __restrict__ out) {
    const int idx = blockIdx.x * 256 + threadIdx.x;   // MM*NN threads
    float s = bias[idx & (NN - 1)];
#pragma unroll
    for (int c = 0; c < KSPLIT; ++c)
        s += part[(size_t)c * MM * NN + idx];
    out[idx] = s;
}

// ---------------------------------------------------------------------------
// Fallback path (only if ws too small): bias-init + atomic gemm (R0 style).
// ---------------------------------------------------------------------------
__global__ __launch_bounds__(256) void init_kernel(const float* __restrict__ bias,
                                                   float* __restrict__ out) {
    int idx = blockIdx.x * 256 + threadIdx.x;
    out[idx] = bias[idx & (NN - 1)];
}

__global__ __launch_bounds__(256, 4) void gemm_atomic(const float* __restrict__ W,
                                                      const float* __restrict__ wsinv,
                                                      const float* __restrict__ ws,
                                                      float* __restrict__ out) {
    const int n  = blockIdx.x * 256 + threadIdx.x;
    const int k0 = blockIdx.y * KC;

    __shared__ float sxq[KC * MM];
    {
        const f32x4* src = (const f32x4*)(ws + XQT_OFF + (size_t)k0 * MM);
        ((f32x4*)sxq)[threadIdx.x]       = src[threadIdx.x];
        ((f32x4*)sxq)[threadIdx.x + 256] = src[threadIdx.x + 256];
    }
    __syncthreads();

    f32x2 acc[4];
#pragma unroll
    for (int i = 0; i < 4; ++i) acc[i] = (f32x2)0.0f;

    const float* Wp = W + (size_t)k0 * NN + n;
#pragma unroll 8
    for (int k = 0; k < KC; ++k) {
        float w = Wp[(size_t)k * NN];
        const f32x2* a2 = (const f32x2*)(sxq + k * MM);
        acc[0] += a2[0] * w;
        acc[1] += a2[1] * w;
        acc[2] += a2[2] * w;
        acc[3] += a2[3] * w;
    }

    const float wsn = wsinv[n];
#pragma unroll
    for (int i = 0; i < 4; ++i) {
        unsafeAtomicAdd(out + (size_t)(2 * i + 0) * NN + n, acc[i].x * (ws[2 * i + 0] * wsn));
        unsafeAtomicAdd(out + (size_t)(2 * i + 1) * NN + n, acc[i].y * (ws[2 * i + 1] * wsn));
    }
}

extern "C" void kernel_launch(void* const* d_in, const int* in_sizes, int n_in,
                              void* d_out, int out_size, void* d_ws, size_t ws_size,
                              hipStream_t stream) {
    const float* x     = (const float*)d_in[0];   // [M,K] f32
    const float* W     = (const float*)d_in[1];   // [K,N] f32 (fp8 values)
    const float* wsinv = (const float*)d_in[2];   // [N]   f32
    const float* bias  = (const float*)d_in[3];   // [N]   f32
    float* out = (float*)d_out;                   // [M,N] f32
    float* ws  = (float*)d_ws;

    const size_t need = (size_t)(PART_OFF + (size_t)KSPLIT * MM * NN) * sizeof(float);

    prep_kernel<<<MM, 256, 0, stream>>>(x, ws);

    if (ws_size >= need) {
        float* part = ws + PART_OFF;
        gemm_partial<<<dim3(NN / 256, KSPLIT), 256, 0, stream>>>(W, wsinv, ws, part);
        reduce_kernel<<<(MM * NN) / 256, 256, 0, stream>>>(part, bias, out);
    } else {
        init_kernel<<<(MM * NN) / 256, 256, 0, stream>>>(bias, out);
        gemm_atomic<<<dim3(NN / 256, KSPLIT), 256, 0, stream>>>(W, wsinv, ws, out);
    }
}